// Round 4
// baseline (357.534 us; speedup 1.0000x reference)
//
#include <hip/hip_runtime.h>
#include <math.h>

#define NN   20000
#define EE   320000
#define ETOT 340000
#define FIN  128
#define HH   4
#define CC   64
#define HC   256
#define GG   64
#define BN_EPS 1e-5f

// ---------------- GEMM: C[M,Nc] = A[M,K] @ B[K,Nc], row-major fp32 ----------------
// BM=64, BN=64, BK=32, 256 threads, 4x4 outputs/thread.
__global__ __launch_bounds__(256) void gemm_kernel(const float* __restrict__ A,
        const float* __restrict__ B, float* __restrict__ Cmat,
        int M, int K, int Nc) {
    __shared__ float sAT[32][68];   // [k][row]
    __shared__ float sB[32][68];    // [k][col]
    int t = threadIdx.x;
    int col0 = blockIdx.x * 64;
    int row0 = blockIdx.y * 64;
    int tx = t & 15, ty = t >> 4;
    float acc[4][4] = {};
    for (int k0 = 0; k0 < K; k0 += 32) {
        #pragma unroll
        for (int i = 0; i < 2; ++i) {
            int e = t + i * 256;
            int r = e >> 3, c4 = e & 7;
            int gr = row0 + r;
            float4 v = make_float4(0.f, 0.f, 0.f, 0.f);
            if (gr < M) v = *(const float4*)&A[(size_t)gr * K + k0 + c4 * 4];
            sAT[c4 * 4 + 0][r] = v.x;
            sAT[c4 * 4 + 1][r] = v.y;
            sAT[c4 * 4 + 2][r] = v.z;
            sAT[c4 * 4 + 3][r] = v.w;
        }
        #pragma unroll
        for (int i = 0; i < 2; ++i) {
            int e = t + i * 256;
            int r = e >> 4, c4 = e & 15;
            float4 v = *(const float4*)&B[(size_t)(k0 + r) * Nc + col0 + c4 * 4];
            *(float4*)&sB[r][c4 * 4] = v;
        }
        __syncthreads();
        #pragma unroll
        for (int kk = 0; kk < 32; ++kk) {
            float4 a = *(const float4*)&sAT[kk][ty * 4];
            float4 b = *(const float4*)&sB[kk][tx * 4];
            acc[0][0] += a.x * b.x; acc[0][1] += a.x * b.y; acc[0][2] += a.x * b.z; acc[0][3] += a.x * b.w;
            acc[1][0] += a.y * b.x; acc[1][1] += a.y * b.y; acc[1][2] += a.y * b.z; acc[1][3] += a.y * b.w;
            acc[2][0] += a.z * b.x; acc[2][1] += a.z * b.y; acc[2][2] += a.z * b.z; acc[2][3] += a.z * b.w;
            acc[3][0] += a.w * b.x; acc[3][1] += a.w * b.y; acc[3][2] += a.w * b.z; acc[3][3] += a.w * b.w;
        }
        __syncthreads();
    }
    #pragma unroll
    for (int j = 0; j < 4; ++j) {
        int gr = row0 + ty * 4 + j;
        if (gr < M) {
            float4 v = make_float4(acc[j][0], acc[j][1], acc[j][2], acc[j][3]);
            *(float4*)&Cmat[(size_t)gr * Nc + col0 + tx * 4] = v;
        }
    }
}

// ---------------- W column permute: Wp[f][c*4+h] = W[f][h*64+c] -------------------
// So h4 = x @ Wp has layout [N][C][H] (head-minor) with unchanged GEMM.
__global__ void permW_kernel(const float* __restrict__ W, float* __restrict__ Wp, int F) {
    int i = blockIdx.x * 256 + threadIdx.x;
    if (i >= F * 256) return;
    int col = i & 255;            // output col = c*4 + h
    int h = col & 3, c = col >> 2;
    int f = i >> 8;
    Wp[i] = W[f * 256 + h * 64 + c];
}

// ---------------- attention logits from h4 [N][C][H] ------------------------------
// wave per node: lane=c loads float4 (4 head values), butterfly-reduce 8 dots.
__global__ __launch_bounds__(256) void att_kernel(const float* __restrict__ h4,
        const float* __restrict__ a_src, const float* __restrict__ a_dst,
        float4* __restrict__ es4, float4* __restrict__ ed4) {
    int n = blockIdx.x * 4 + (threadIdx.x >> 6);
    if (n >= NN) return;
    int lane = threadIdx.x & 63;
    float4 v = *(const float4*)&h4[(size_t)n * HC + lane * 4];
    float s0 = v.x * a_src[0 * CC + lane];
    float s1 = v.y * a_src[1 * CC + lane];
    float s2 = v.z * a_src[2 * CC + lane];
    float s3 = v.w * a_src[3 * CC + lane];
    float d0 = v.x * a_dst[0 * CC + lane];
    float d1 = v.y * a_dst[1 * CC + lane];
    float d2 = v.z * a_dst[2 * CC + lane];
    float d3 = v.w * a_dst[3 * CC + lane];
    #pragma unroll
    for (int off = 32; off; off >>= 1) {
        s0 += __shfl_down(s0, off); s1 += __shfl_down(s1, off);
        s2 += __shfl_down(s2, off); s3 += __shfl_down(s3, off);
        d0 += __shfl_down(d0, off); d1 += __shfl_down(d1, off);
        d2 += __shfl_down(d2, off); d3 += __shfl_down(d3, off);
    }
    if (lane == 0) {
        es4[n] = make_float4(s0, s1, s2, s3);
        ed4[n] = make_float4(d0, d1, d2, d3);
    }
}

// ---------------- CSR build ----------------
__global__ void count_kernel(const int* __restrict__ ei, int* __restrict__ deg) {
    int i = blockIdx.x * 256 + threadIdx.x;
    if (i >= ETOT) return;
    int d = (i < EE) ? ei[EE + i] : (i - EE);
    atomicAdd(&deg[d], 1);
}

__global__ __launch_bounds__(256) void scan1(const int* __restrict__ deg,
        int* __restrict__ off, int* __restrict__ part) {
    __shared__ int buf[256];
    int b = blockIdx.x, t = threadIdx.x;
    int i = b * 256 + t;
    int v = (i < NN) ? deg[i] : 0;
    buf[t] = v; __syncthreads();
    for (int s = 1; s < 256; s <<= 1) {
        int x = (t >= s) ? buf[t - s] : 0;
        __syncthreads();
        buf[t] += x;
        __syncthreads();
    }
    int incl = buf[t];
    if (i < NN) off[i] = incl - v;
    if (t == 255) part[b] = incl;
}

__global__ __launch_bounds__(128) void scan2(int* __restrict__ part, int nb) {
    __shared__ int buf[128];
    int t = threadIdx.x;
    int v = (t < nb) ? part[t] : 0;
    buf[t] = v; __syncthreads();
    for (int s = 1; s < 128; s <<= 1) {
        int x = (t >= s) ? buf[t - s] : 0;
        __syncthreads();
        buf[t] += x;
        __syncthreads();
    }
    if (t < nb) part[t] = buf[t] - v;
}

__global__ __launch_bounds__(256) void scan3(int* __restrict__ off, const int* __restrict__ part) {
    int b = blockIdx.x, t = threadIdx.x;
    int i = b * 256 + t;
    if (i < NN) off[i] += part[b];
    if (i == 0) off[NN] = ETOT;
}

__global__ void fill_kernel(const int* __restrict__ ei, const int* __restrict__ off,
        int* __restrict__ cursor, int* __restrict__ csr_src) {
    int i = blockIdx.x * 256 + threadIdx.x;
    if (i >= ETOT) return;
    int s, d;
    if (i < EE) { s = ei[i]; d = ei[EE + i]; } else { s = i - EE; d = i - EE; }
    int pos = atomicAdd(&cursor[d], 1);
    csr_src[off[d] + pos] = s;
}

// ---------------- per-destination GAT aggregation (h4 layout, dwordx4 gather) ------
// 4 waves/block; wave = node; lane = channel; one float4 load per edge per lane.
__global__ __launch_bounds__(256) void aggr_kernel(const float* __restrict__ h4,
        const float4* __restrict__ es4, const float4* __restrict__ ed4,
        const int* __restrict__ off, const int* __restrict__ csr_src,
        const float* __restrict__ bias, float* __restrict__ out) {
    int n = blockIdx.x * 4 + (threadIdx.x >> 6);
    if (n >= NN) return;
    int lane = threadIdx.x & 63;
    float4 edn = ed4[n];
    float4 acc = make_float4(0.f, 0.f, 0.f, 0.f);
    float4 ssum = make_float4(0.f, 0.f, 0.f, 0.f);
    int beg = off[n], end = off[n + 1];
    int src = csr_src[beg];                   // deg >= 1 (self-loop)
    for (int j = beg; j < end; ++j) {
        int nsrc = (j + 1 < end) ? csr_src[j + 1] : 0;
        float4 esv = es4[src];
        float4 v = *(const float4*)&h4[(size_t)src * HC + lane * 4];
        float e0 = esv.x + edn.x; e0 = fmaxf(e0, 0.2f * e0); float w0 = __expf(e0);
        float e1 = esv.y + edn.y; e1 = fmaxf(e1, 0.2f * e1); float w1 = __expf(e1);
        float e2 = esv.z + edn.z; e2 = fmaxf(e2, 0.2f * e2); float w2 = __expf(e2);
        float e3 = esv.w + edn.w; e3 = fmaxf(e3, 0.2f * e3); float w3 = __expf(e3);
        acc.x += w0 * v.x; ssum.x += w0;
        acc.y += w1 * v.y; ssum.y += w1;
        acc.z += w2 * v.z; ssum.z += w2;
        acc.w += w3 * v.w; ssum.w += w3;
        src = nsrc;
    }
    float val = 0.25f * (acc.x / (ssum.x + 1e-16f) + acc.y / (ssum.y + 1e-16f) +
                         acc.z / (ssum.z + 1e-16f) + acc.w / (ssum.w + 1e-16f)) + bias[lane];
    out[n * CC + lane] = val;
}

// ---------------- BN statistics: stats[0:64]=sum, stats[64:128]=sumsq ----------------
__global__ __launch_bounds__(256) void bnstat_kernel(const float* __restrict__ x,
        float* __restrict__ stats) {
    int t = threadIdx.x;
    int ch = t & 63, slice = t >> 6;
    float s = 0.f, q = 0.f;
    for (int n = blockIdx.x * 4 + slice; n < NN; n += gridDim.x * 4) {
        float v = x[n * CC + ch];
        s += v; q += v * v;
    }
    __shared__ float ls[4][64], lq[4][64];
    ls[slice][ch] = s; lq[slice][ch] = q;
    __syncthreads();
    if (slice == 0) {
        s = ls[0][ch] + ls[1][ch] + ls[2][ch] + ls[3][ch];
        q = lq[0][ch] + lq[1][ch] + lq[2][ch] + lq[3][ch];
        atomicAdd(&stats[ch], s);
        atomicAdd(&stats[CC + ch], q);
    }
}

__device__ __forceinline__ float gelu_exact(float v) {
    return 0.5f * v * (1.f + erff(v * 0.70710678118654752f));
}

// layer1: out = gelu(bn(gat) + skip + bskip)
__global__ __launch_bounds__(256) void bnapply1_kernel(const float* __restrict__ gout,
        const float* __restrict__ stats, const float* __restrict__ g,
        const float* __restrict__ be, const float* __restrict__ skip,
        const float* __restrict__ bskip, float* __restrict__ outm) {
    int i = blockIdx.x * 256 + threadIdx.x;
    if (i >= NN * CC) return;
    int ch = i & 63;
    float mu  = stats[ch] * (1.f / NN);
    float var = stats[CC + ch] * (1.f / NN) - mu * mu;
    float inv = rsqrtf(var + BN_EPS);
    float v = (gout[i] - mu) * inv * g[ch] + be[ch] + skip[i] + bskip[ch];
    outm[i] = gelu_exact(v);
}

// layer2: out = gelu(bn(gat) + resid)
__global__ __launch_bounds__(256) void bnapply2_kernel(const float* __restrict__ gout,
        const float* __restrict__ stats, const float* __restrict__ g,
        const float* __restrict__ be, const float* __restrict__ resid,
        float* __restrict__ outm) {
    int i = blockIdx.x * 256 + threadIdx.x;
    if (i >= NN * CC) return;
    int ch = i & 63;
    float mu  = stats[ch] * (1.f / NN);
    float var = stats[CC + ch] * (1.f / NN) - mu * mu;
    float inv = rsqrtf(var + BN_EPS);
    float v = (gout[i] - mu) * inv * g[ch] + be[ch] + resid[i];
    outm[i] = gelu_exact(v);
}

// ---------------- pooling (batch_idx sorted -> boundaries, no atomics) -------------
__global__ void gbound_kernel(const int* __restrict__ bidx, int* __restrict__ gstart) {
    int i = blockIdx.x * 256 + threadIdx.x;
    if (i >= NN) return;
    int cur = bidx[i];
    if (i == 0) {
        for (int g = 0; g <= cur; ++g) gstart[g] = 0;
    } else {
        int prev = bidx[i - 1];
        for (int g = prev + 1; g <= cur; ++g) gstart[g] = i;
    }
    if (i == NN - 1) {
        for (int g = cur + 1; g <= GG; ++g) gstart[g] = NN;
    }
}

__global__ __launch_bounds__(1024) void pool_kernel(const float* __restrict__ h2,
        const int* __restrict__ gstart, float* __restrict__ out) {
    __shared__ float4 sdata[64][17];
    int g = blockIdx.x;
    int t = threadIdx.x;
    int c4 = t & 15;
    int slice = t >> 4;
    int start = gstart[g], end = gstart[g + 1];
    float4 acc = make_float4(0.f, 0.f, 0.f, 0.f);
    for (int n = start + slice; n < end; n += 64) {
        float4 v = *(const float4*)&h2[(size_t)n * CC + c4 * 4];
        acc.x += v.x; acc.y += v.y; acc.z += v.z; acc.w += v.w;
    }
    sdata[slice][c4] = acc;
    __syncthreads();
    #pragma unroll
    for (int s = 32; s >= 1; s >>= 1) {
        if (slice < s) {
            float4 o = sdata[slice + s][c4];
            acc.x += o.x; acc.y += o.y; acc.z += o.z; acc.w += o.w;
            sdata[slice][c4] = acc;
        }
        __syncthreads();
    }
    if (slice == 0) {
        int cnt = end - start;
        float inv = 1.f / (float)((cnt > 0) ? cnt : 1);
        float4 r = make_float4(acc.x * inv, acc.y * inv, acc.z * inv, acc.w * inv);
        *(float4*)&out[g * CC + c4 * 4] = r;
    }
}

extern "C" void kernel_launch(void* const* d_in, const int* in_sizes, int n_in,
                              void* d_out, int out_size, void* d_ws, size_t ws_size,
                              hipStream_t stream) {
    const float* x      = (const float*)d_in[0];
    const float* W1     = (const float*)d_in[1];
    const float* a_src1 = (const float*)d_in[2];
    const float* a_dst1 = (const float*)d_in[3];
    const float* b1     = (const float*)d_in[4];
    const float* Wskip  = (const float*)d_in[5];
    const float* bskip  = (const float*)d_in[6];
    const float* g1     = (const float*)d_in[7];
    const float* be1    = (const float*)d_in[8];
    const float* W2     = (const float*)d_in[9];
    const float* a_src2 = (const float*)d_in[10];
    const float* a_dst2 = (const float*)d_in[11];
    const float* b2     = (const float*)d_in[12];
    const float* g2     = (const float*)d_in[13];
    const float* be2    = (const float*)d_in[14];
    const int*   ei     = (const int*)d_in[15];
    const int*   bidx   = (const int*)d_in[16];
    float* out = (float*)d_out;

    char* w = (char*)d_ws;
    size_t o = 0;
    auto alloc = [&](size_t bytes) -> void* {
        void* p = w + o;
        o = (o + bytes + 255) & ~(size_t)255;
        return p;
    };

    float* h4   = (float*)alloc((size_t)NN * HC * 4);  // projections, [N][C][H] layout
    float4* es4 = (float4*)alloc((size_t)NN * 16);
    float4* ed4 = (float4*)alloc((size_t)NN * 16);
    float* skip = (float*)alloc((size_t)NN * CC * 4);  // layer1 skip; reused as h2 output
    float* gout = (float*)alloc((size_t)NN * CC * 4);
    float* hmid = (float*)alloc((size_t)NN * CC * 4);
    float* W1p  = (float*)alloc((size_t)FIN * HC * 4);
    float* W2p  = (float*)alloc((size_t)CC * HC * 4);
    int* off    = (int*)alloc((size_t)(NN + 1) * 4);
    int* csr    = (int*)alloc((size_t)ETOT * 4);
    int* gstart = (int*)alloc((size_t)(GG + 1) * 4);
    // ---- zero region (contiguous) ----
    char* zbase = w + o;
    int* deg    = (int*)alloc((size_t)NN * 4);
    int* cursor = (int*)alloc((size_t)NN * 4);
    int* part   = (int*)alloc(128 * 4);
    float* stats1 = (float*)alloc(128 * 4);
    float* stats2 = (float*)alloc(128 * 4);
    size_t zbytes = (size_t)((w + o) - zbase);
    float* h2 = skip;  // reuse

    hipMemsetAsync(zbase, 0, zbytes, stream);

    int ebk = (ETOT + 255) / 256;
    int nbk = (NN + 255) / 256;

    // CSR build (shared by both layers) + pool boundaries + weight permutes
    count_kernel<<<ebk, 256, 0, stream>>>(ei, deg);
    scan1<<<nbk, 256, 0, stream>>>(deg, off, part);
    scan2<<<1, 128, 0, stream>>>(part, nbk);
    scan3<<<nbk, 256, 0, stream>>>(off, part);
    fill_kernel<<<ebk, 256, 0, stream>>>(ei, off, cursor, csr);
    gbound_kernel<<<nbk, 256, 0, stream>>>(bidx, gstart);
    permW_kernel<<<(FIN * 256 + 255) / 256, 256, 0, stream>>>(W1, W1p, FIN);
    permW_kernel<<<(CC * 256 + 255) / 256, 256, 0, stream>>>(W2, W2p, CC);

    dim3 gemm_blk(256);
    dim3 g_h(HC / 64, (NN + 63) / 64);
    dim3 g_s(CC / 64, (NN + 63) / 64);
    int nodeblk = (NN + 3) / 4;

    // ---- layer 1 ----
    gemm_kernel<<<g_h, gemm_blk, 0, stream>>>(x, W1p, h4, NN, FIN, HC);
    gemm_kernel<<<g_s, gemm_blk, 0, stream>>>(x, Wskip, skip, NN, FIN, CC);
    att_kernel<<<nodeblk, 256, 0, stream>>>(h4, a_src1, a_dst1, es4, ed4);
    aggr_kernel<<<nodeblk, 256, 0, stream>>>(h4, es4, ed4, off, csr, b1, gout);
    bnstat_kernel<<<128, 256, 0, stream>>>(gout, stats1);
    bnapply1_kernel<<<(NN * CC + 255) / 256, 256, 0, stream>>>(
        gout, stats1, g1, be1, skip, bskip, hmid);

    // ---- layer 2 ----
    gemm_kernel<<<g_h, gemm_blk, 0, stream>>>(hmid, W2p, h4, NN, CC, HC);
    att_kernel<<<nodeblk, 256, 0, stream>>>(h4, a_src2, a_dst2, es4, ed4);
    aggr_kernel<<<nodeblk, 256, 0, stream>>>(h4, es4, ed4, off, csr, b2, gout);
    bnstat_kernel<<<128, 256, 0, stream>>>(gout, stats2);
    bnapply2_kernel<<<(NN * CC + 255) / 256, 256, 0, stream>>>(
        gout, stats2, g2, be2, hmid, h2);

    // ---- pool ----
    pool_kernel<<<GG, 1024, 0, stream>>>(h2, gstart, out);
}

// Round 5
// 333.791 us; speedup vs baseline: 1.0711x; 1.0711x over previous
//
#include <hip/hip_runtime.h>
#include <math.h>

#define NN   20000
#define EE   320000
#define ETOT 340000
#define FIN  128
#define HH   4
#define CC   64
#define HC   256
#define GG   64
#define BN_EPS 1e-5f

// ---------------- GEMM: C[M,Nc] = A[M,K] @ B[K,Nc], row-major fp32 ----------------
__global__ __launch_bounds__(256) void gemm_kernel(const float* __restrict__ A,
        const float* __restrict__ B, float* __restrict__ Cmat,
        int M, int K, int Nc) {
    __shared__ float sAT[32][68];   // [k][row]
    __shared__ float sB[32][68];    // [k][col]
    int t = threadIdx.x;
    int col0 = blockIdx.x * 64;
    int row0 = blockIdx.y * 64;
    int tx = t & 15, ty = t >> 4;
    float acc[4][4] = {};
    for (int k0 = 0; k0 < K; k0 += 32) {
        #pragma unroll
        for (int i = 0; i < 2; ++i) {
            int e = t + i * 256;
            int r = e >> 3, c4 = e & 7;
            int gr = row0 + r;
            float4 v = make_float4(0.f, 0.f, 0.f, 0.f);
            if (gr < M) v = *(const float4*)&A[(size_t)gr * K + k0 + c4 * 4];
            sAT[c4 * 4 + 0][r] = v.x;
            sAT[c4 * 4 + 1][r] = v.y;
            sAT[c4 * 4 + 2][r] = v.z;
            sAT[c4 * 4 + 3][r] = v.w;
        }
        #pragma unroll
        for (int i = 0; i < 2; ++i) {
            int e = t + i * 256;
            int r = e >> 4, c4 = e & 15;
            float4 v = *(const float4*)&B[(size_t)(k0 + r) * Nc + col0 + c4 * 4];
            *(float4*)&sB[r][c4 * 4] = v;
        }
        __syncthreads();
        #pragma unroll
        for (int kk = 0; kk < 32; ++kk) {
            float4 a = *(const float4*)&sAT[kk][ty * 4];
            float4 b = *(const float4*)&sB[kk][tx * 4];
            acc[0][0] += a.x * b.x; acc[0][1] += a.x * b.y; acc[0][2] += a.x * b.z; acc[0][3] += a.x * b.w;
            acc[1][0] += a.y * b.x; acc[1][1] += a.y * b.y; acc[1][2] += a.y * b.z; acc[1][3] += a.y * b.w;
            acc[2][0] += a.z * b.x; acc[2][1] += a.z * b.y; acc[2][2] += a.z * b.z; acc[2][3] += a.z * b.w;
            acc[3][0] += a.w * b.x; acc[3][1] += a.w * b.y; acc[3][2] += a.w * b.z; acc[3][3] += a.w * b.w;
        }
        __syncthreads();
    }
    #pragma unroll
    for (int j = 0; j < 4; ++j) {
        int gr = row0 + ty * 4 + j;
        if (gr < M) {
            float4 v = make_float4(acc[j][0], acc[j][1], acc[j][2], acc[j][3]);
            *(float4*)&Cmat[(size_t)gr * Nc + col0 + tx * 4] = v;
        }
    }
}

// ---------------- misc fused: gbound + permW1 + permW2 ----------------------------
// blocks [0,79): graph boundaries; [79,207): permute W1; [207,271): permute W2.
__global__ void misc_kernel(const int* __restrict__ bidx, int* __restrict__ gstart,
        const float* __restrict__ W1, float* __restrict__ W1p,
        const float* __restrict__ W2, float* __restrict__ W2p) {
    int b = blockIdx.x, t = threadIdx.x;
    if (b < 79) {
        int i = b * 256 + t;
        if (i >= NN) return;
        int cur = bidx[i];
        if (i == 0) {
            for (int g = 0; g <= cur; ++g) gstart[g] = 0;
        } else {
            int prev = bidx[i - 1];
            for (int g = prev + 1; g <= cur; ++g) gstart[g] = i;
        }
        if (i == NN - 1) {
            for (int g = cur + 1; g <= GG; ++g) gstart[g] = NN;
        }
    } else if (b < 207) {
        int i = (b - 79) * 256 + t;       // i < FIN*256
        int col = i & 255;
        int h = col & 3, c = col >> 2;
        int f = i >> 8;
        W1p[i] = W1[f * 256 + h * 64 + c];
    } else {
        int i = (b - 207) * 256 + t;      // i < CC*256
        int col = i & 255;
        int h = col & 3, c = col >> 2;
        int f = i >> 8;
        W2p[i] = W2[f * 256 + h * 64 + c];
    }
}

// ---------------- attention logits from h4 [N][C][H] ------------------------------
__global__ __launch_bounds__(256) void att_kernel(const float* __restrict__ h4,
        const float* __restrict__ a_src, const float* __restrict__ a_dst,
        float4* __restrict__ es4, float4* __restrict__ ed4) {
    int n = blockIdx.x * 4 + (threadIdx.x >> 6);
    if (n >= NN) return;
    int lane = threadIdx.x & 63;
    float4 v = *(const float4*)&h4[(size_t)n * HC + lane * 4];
    float s0 = v.x * a_src[0 * CC + lane];
    float s1 = v.y * a_src[1 * CC + lane];
    float s2 = v.z * a_src[2 * CC + lane];
    float s3 = v.w * a_src[3 * CC + lane];
    float d0 = v.x * a_dst[0 * CC + lane];
    float d1 = v.y * a_dst[1 * CC + lane];
    float d2 = v.z * a_dst[2 * CC + lane];
    float d3 = v.w * a_dst[3 * CC + lane];
    #pragma unroll
    for (int off = 32; off; off >>= 1) {
        s0 += __shfl_down(s0, off); s1 += __shfl_down(s1, off);
        s2 += __shfl_down(s2, off); s3 += __shfl_down(s3, off);
        d0 += __shfl_down(d0, off); d1 += __shfl_down(d1, off);
        d2 += __shfl_down(d2, off); d3 += __shfl_down(d3, off);
    }
    if (lane == 0) {
        es4[n] = make_float4(s0, s1, s2, s3);
        ed4[n] = make_float4(d0, d1, d2, d3);
    }
}

// ---------------- CSR build ----------------
__global__ void count_kernel(const int* __restrict__ ei, int* __restrict__ deg) {
    int i = blockIdx.x * 256 + threadIdx.x;
    if (i >= ETOT) return;
    int d = (i < EE) ? ei[EE + i] : (i - EE);
    atomicAdd(&deg[d], 1);
}

__global__ __launch_bounds__(256) void scan1(const int* __restrict__ deg,
        int* __restrict__ off, int* __restrict__ part) {
    __shared__ int buf[256];
    int b = blockIdx.x, t = threadIdx.x;
    int i = b * 256 + t;
    int v = (i < NN) ? deg[i] : 0;
    buf[t] = v; __syncthreads();
    for (int s = 1; s < 256; s <<= 1) {
        int x = (t >= s) ? buf[t - s] : 0;
        __syncthreads();
        buf[t] += x;
        __syncthreads();
    }
    int incl = buf[t];
    if (i < NN) off[i] = incl - v;
    if (t == 255) part[b] = incl;
}

// scan of block partials folded in: every block scans the 79 partials in LDS.
__global__ __launch_bounds__(256) void scan23(int* __restrict__ off,
        const int* __restrict__ part) {
    __shared__ int buf[128];
    int t = threadIdx.x, b = blockIdx.x;
    if (t < 128) buf[t] = (t < (int)gridDim.x) ? part[t] : 0;
    __syncthreads();
    for (int s = 1; s < 128; s <<= 1) {
        int x = (t >= s && t < 128) ? buf[t - s] : 0;
        __syncthreads();
        if (t < 128) buf[t] += x;
        __syncthreads();
    }
    int prefix = (b == 0) ? 0 : buf[b - 1];
    int i = b * 256 + t;
    if (i < NN) off[i] += prefix;
    if (i == 0) off[NN] = ETOT;
}

__global__ void fill_kernel(const int* __restrict__ ei, const int* __restrict__ off,
        int* __restrict__ cursor, int* __restrict__ csr_src) {
    int i = blockIdx.x * 256 + threadIdx.x;
    if (i >= ETOT) return;
    int s, d;
    if (i < EE) { s = ei[i]; d = ei[EE + i]; } else { s = i - EE; d = i - EE; }
    int pos = atomicAdd(&cursor[d], 1);
    csr_src[off[d] + pos] = s;
}

// ---------------- per-destination GAT aggregation ----------------------------------
__device__ __forceinline__ void edge_acc(const float4 esv, const float4 v,
        const float4 edn, float4& acc, float4& ssum) {
    float e0 = esv.x + edn.x; e0 = fmaxf(e0, 0.2f * e0); float w0 = __expf(e0);
    float e1 = esv.y + edn.y; e1 = fmaxf(e1, 0.2f * e1); float w1 = __expf(e1);
    float e2 = esv.z + edn.z; e2 = fmaxf(e2, 0.2f * e2); float w2 = __expf(e2);
    float e3 = esv.w + edn.w; e3 = fmaxf(e3, 0.2f * e3); float w3 = __expf(e3);
    acc.x += w0 * v.x; ssum.x += w0;
    acc.y += w1 * v.y; ssum.y += w1;
    acc.z += w2 * v.z; ssum.z += w2;
    acc.w += w3 * v.w; ssum.w += w3;
}

// 4 waves/block; wave = node; lane = channel. Edge loop unrolled x4 so each wave
// keeps 12 independent loads in flight (latency hiding), vs 3 before.
__global__ __launch_bounds__(256) void aggr_kernel(const float* __restrict__ h4,
        const float4* __restrict__ es4, const float4* __restrict__ ed4,
        const int* __restrict__ off, const int* __restrict__ csr_src,
        const float* __restrict__ bias, float* __restrict__ out) {
    int n = blockIdx.x * 4 + (threadIdx.x >> 6);
    if (n >= NN) return;
    int lane = threadIdx.x & 63;
    float4 edn = ed4[n];
    float4 acc = make_float4(0.f, 0.f, 0.f, 0.f);
    float4 ssum = make_float4(0.f, 0.f, 0.f, 0.f);
    int beg = off[n], end = off[n + 1];
    int j = beg;
    for (; j + 4 <= end; j += 4) {
        int s0 = csr_src[j + 0];
        int s1 = csr_src[j + 1];
        int s2 = csr_src[j + 2];
        int s3 = csr_src[j + 3];
        float4 E0 = es4[s0];
        float4 E1 = es4[s1];
        float4 E2 = es4[s2];
        float4 E3 = es4[s3];
        float4 v0 = *(const float4*)&h4[(size_t)s0 * HC + lane * 4];
        float4 v1 = *(const float4*)&h4[(size_t)s1 * HC + lane * 4];
        float4 v2 = *(const float4*)&h4[(size_t)s2 * HC + lane * 4];
        float4 v3 = *(const float4*)&h4[(size_t)s3 * HC + lane * 4];
        edge_acc(E0, v0, edn, acc, ssum);
        edge_acc(E1, v1, edn, acc, ssum);
        edge_acc(E2, v2, edn, acc, ssum);
        edge_acc(E3, v3, edn, acc, ssum);
    }
    for (; j < end; ++j) {
        int s = csr_src[j];
        float4 E = es4[s];
        float4 v = *(const float4*)&h4[(size_t)s * HC + lane * 4];
        edge_acc(E, v, edn, acc, ssum);
    }
    float val = 0.25f * (acc.x / (ssum.x + 1e-16f) + acc.y / (ssum.y + 1e-16f) +
                         acc.z / (ssum.z + 1e-16f) + acc.w / (ssum.w + 1e-16f)) + bias[lane];
    out[n * CC + lane] = val;
}

// ---------------- BN statistics: stats[0:64]=sum, stats[64:128]=sumsq ----------------
__global__ __launch_bounds__(256) void bnstat_kernel(const float* __restrict__ x,
        float* __restrict__ stats) {
    int t = threadIdx.x;
    int ch = t & 63, slice = t >> 6;
    float s = 0.f, q = 0.f;
    for (int n = blockIdx.x * 4 + slice; n < NN; n += gridDim.x * 4) {
        float v = x[n * CC + ch];
        s += v; q += v * v;
    }
    __shared__ float ls[4][64], lq[4][64];
    ls[slice][ch] = s; lq[slice][ch] = q;
    __syncthreads();
    if (slice == 0) {
        s = ls[0][ch] + ls[1][ch] + ls[2][ch] + ls[3][ch];
        q = lq[0][ch] + lq[1][ch] + lq[2][ch] + lq[3][ch];
        atomicAdd(&stats[ch], s);
        atomicAdd(&stats[CC + ch], q);
    }
}

__device__ __forceinline__ float gelu_exact(float v) {
    return 0.5f * v * (1.f + erff(v * 0.70710678118654752f));
}

// layer1: out = gelu(bn(gat) + skip + bskip)
__global__ __launch_bounds__(256) void bnapply1_kernel(const float* __restrict__ gout,
        const float* __restrict__ stats, const float* __restrict__ g,
        const float* __restrict__ be, const float* __restrict__ skip,
        const float* __restrict__ bskip, float* __restrict__ outm) {
    int i = blockIdx.x * 256 + threadIdx.x;
    if (i >= NN * CC) return;
    int ch = i & 63;
    float mu  = stats[ch] * (1.f / NN);
    float var = stats[CC + ch] * (1.f / NN) - mu * mu;
    float inv = rsqrtf(var + BN_EPS);
    float v = (gout[i] - mu) * inv * g[ch] + be[ch] + skip[i] + bskip[ch];
    outm[i] = gelu_exact(v);
}

// layer2: out = gelu(bn(gat) + resid)
__global__ __launch_bounds__(256) void bnapply2_kernel(const float* __restrict__ gout,
        const float* __restrict__ stats, const float* __restrict__ g,
        const float* __restrict__ be, const float* __restrict__ resid,
        float* __restrict__ outm) {
    int i = blockIdx.x * 256 + threadIdx.x;
    if (i >= NN * CC) return;
    int ch = i & 63;
    float mu  = stats[ch] * (1.f / NN);
    float var = stats[CC + ch] * (1.f / NN) - mu * mu;
    float inv = rsqrtf(var + BN_EPS);
    float v = (gout[i] - mu) * inv * g[ch] + be[ch] + resid[i];
    outm[i] = gelu_exact(v);
}

// ---------------- pooling ----------------
__global__ __launch_bounds__(1024) void pool_kernel(const float* __restrict__ h2,
        const int* __restrict__ gstart, float* __restrict__ out) {
    __shared__ float4 sdata[64][17];
    int g = blockIdx.x;
    int t = threadIdx.x;
    int c4 = t & 15;
    int slice = t >> 4;
    int start = gstart[g], end = gstart[g + 1];
    float4 acc = make_float4(0.f, 0.f, 0.f, 0.f);
    for (int n = start + slice; n < end; n += 64) {
        float4 v = *(const float4*)&h2[(size_t)n * CC + c4 * 4];
        acc.x += v.x; acc.y += v.y; acc.z += v.z; acc.w += v.w;
    }
    sdata[slice][c4] = acc;
    __syncthreads();
    #pragma unroll
    for (int s = 32; s >= 1; s >>= 1) {
        if (slice < s) {
            float4 o = sdata[slice + s][c4];
            acc.x += o.x; acc.y += o.y; acc.z += o.z; acc.w += o.w;
            sdata[slice][c4] = acc;
        }
        __syncthreads();
    }
    if (slice == 0) {
        int cnt = end - start;
        float inv = 1.f / (float)((cnt > 0) ? cnt : 1);
        float4 r = make_float4(acc.x * inv, acc.y * inv, acc.z * inv, acc.w * inv);
        *(float4*)&out[g * CC + c4 * 4] = r;
    }
}

extern "C" void kernel_launch(void* const* d_in, const int* in_sizes, int n_in,
                              void* d_out, int out_size, void* d_ws, size_t ws_size,
                              hipStream_t stream) {
    const float* x      = (const float*)d_in[0];
    const float* W1     = (const float*)d_in[1];
    const float* a_src1 = (const float*)d_in[2];
    const float* a_dst1 = (const float*)d_in[3];
    const float* b1     = (const float*)d_in[4];
    const float* Wskip  = (const float*)d_in[5];
    const float* bskip  = (const float*)d_in[6];
    const float* g1     = (const float*)d_in[7];
    const float* be1    = (const float*)d_in[8];
    const float* W2     = (const float*)d_in[9];
    const float* a_src2 = (const float*)d_in[10];
    const float* a_dst2 = (const float*)d_in[11];
    const float* b2     = (const float*)d_in[12];
    const float* g2     = (const float*)d_in[13];
    const float* be2    = (const float*)d_in[14];
    const int*   ei     = (const int*)d_in[15];
    const int*   bidx   = (const int*)d_in[16];
    float* out = (float*)d_out;

    char* w = (char*)d_ws;
    size_t o = 0;
    auto alloc = [&](size_t bytes) -> void* {
        void* p = w + o;
        o = (o + bytes + 255) & ~(size_t)255;
        return p;
    };

    float* h4   = (float*)alloc((size_t)NN * HC * 4);  // projections, [N][C][H] layout
    float4* es4 = (float4*)alloc((size_t)NN * 16);
    float4* ed4 = (float4*)alloc((size_t)NN * 16);
    float* skip = (float*)alloc((size_t)NN * CC * 4);  // layer1 skip; reused as h2 output
    float* gout = (float*)alloc((size_t)NN * CC * 4);
    float* hmid = (float*)alloc((size_t)NN * CC * 4);
    float* W1p  = (float*)alloc((size_t)FIN * HC * 4);
    float* W2p  = (float*)alloc((size_t)CC * HC * 4);
    int* off    = (int*)alloc((size_t)(NN + 1) * 4);
    int* csr    = (int*)alloc((size_t)ETOT * 4);
    int* gstart = (int*)alloc((size_t)(GG + 1) * 4);
    // ---- zero region (contiguous) ----
    char* zbase = w + o;
    int* deg    = (int*)alloc((size_t)NN * 4);
    int* cursor = (int*)alloc((size_t)NN * 4);
    int* part   = (int*)alloc(128 * 4);
    float* stats1 = (float*)alloc(128 * 4);
    float* stats2 = (float*)alloc(128 * 4);
    size_t zbytes = (size_t)((w + o) - zbase);
    float* h2 = skip;  // reuse

    hipMemsetAsync(zbase, 0, zbytes, stream);

    int ebk = (ETOT + 255) / 256;
    int nbk = (NN + 255) / 256;     // 79

    // preprocessing: CSR + boundaries + weight permutes
    misc_kernel<<<79 + 128 + 64, 256, 0, stream>>>(bidx, gstart, W1, W1p, W2, W2p);
    count_kernel<<<ebk, 256, 0, stream>>>(ei, deg);
    scan1<<<nbk, 256, 0, stream>>>(deg, off, part);
    scan23<<<nbk, 256, 0, stream>>>(off, part);
    fill_kernel<<<ebk, 256, 0, stream>>>(ei, off, cursor, csr);

    dim3 gemm_blk(256);
    dim3 g_h(HC / 64, (NN + 63) / 64);
    dim3 g_s(CC / 64, (NN + 63) / 64);
    int nodeblk = (NN + 3) / 4;

    // ---- layer 1 ----
    gemm_kernel<<<g_h, gemm_blk, 0, stream>>>(x, W1p, h4, NN, FIN, HC);
    gemm_kernel<<<g_s, gemm_blk, 0, stream>>>(x, Wskip, skip, NN, FIN, CC);
    att_kernel<<<nodeblk, 256, 0, stream>>>(h4, a_src1, a_dst1, es4, ed4);
    aggr_kernel<<<nodeblk, 256, 0, stream>>>(h4, es4, ed4, off, csr, b1, gout);
    bnstat_kernel<<<128, 256, 0, stream>>>(gout, stats1);
    bnapply1_kernel<<<(NN * CC + 255) / 256, 256, 0, stream>>>(
        gout, stats1, g1, be1, skip, bskip, hmid);

    // ---- layer 2 ----
    gemm_kernel<<<g_h, gemm_blk, 0, stream>>>(hmid, W2p, h4, NN, CC, HC);
    att_kernel<<<nodeblk, 256, 0, stream>>>(h4, a_src2, a_dst2, es4, ed4);
    aggr_kernel<<<nodeblk, 256, 0, stream>>>(h4, es4, ed4, off, csr, b2, gout);
    bnstat_kernel<<<128, 256, 0, stream>>>(gout, stats2);
    bnapply2_kernel<<<(NN * CC + 255) / 256, 256, 0, stream>>>(
        gout, stats2, g2, be2, hmid, h2);

    // ---- pool ----
    pool_kernel<<<GG, 1024, 0, stream>>>(h2, gstart, out);
}

// Round 6
// 299.866 us; speedup vs baseline: 1.1923x; 1.1131x over previous
//
#include <hip/hip_runtime.h>
#include <math.h>

#define NN   20000
#define EE   320000
#define ETOT 340000
#define FIN  128
#define HH   4
#define CC   64
#define HC   256
#define GG   64
#define BN_EPS 1e-5f

__device__ __forceinline__ unsigned short f2bf(float f) {
    unsigned u = __float_as_uint(f);
    unsigned r = (u + 0x7FFF + ((u >> 16) & 1)) >> 16;   // RNE
    return (unsigned short)r;
}
__device__ __forceinline__ float bf2f(unsigned short u) {
    return __uint_as_float((unsigned)u << 16);
}

// ---------------- GEMM fp32 out: C[M,Nc] = A[M,K] @ B[K,Nc] ----------------------
__global__ __launch_bounds__(256) void gemm_kernel(const float* __restrict__ A,
        const float* __restrict__ B, float* __restrict__ Cmat,
        int M, int K, int Nc) {
    __shared__ float sAT[32][68];
    __shared__ float sB[32][68];
    int t = threadIdx.x;
    int col0 = blockIdx.x * 64;
    int row0 = blockIdx.y * 64;
    int tx = t & 15, ty = t >> 4;
    float acc[4][4] = {};
    for (int k0 = 0; k0 < K; k0 += 32) {
        #pragma unroll
        for (int i = 0; i < 2; ++i) {
            int e = t + i * 256;
            int r = e >> 3, c4 = e & 7;
            int gr = row0 + r;
            float4 v = make_float4(0.f, 0.f, 0.f, 0.f);
            if (gr < M) v = *(const float4*)&A[(size_t)gr * K + k0 + c4 * 4];
            sAT[c4 * 4 + 0][r] = v.x;
            sAT[c4 * 4 + 1][r] = v.y;
            sAT[c4 * 4 + 2][r] = v.z;
            sAT[c4 * 4 + 3][r] = v.w;
        }
        #pragma unroll
        for (int i = 0; i < 2; ++i) {
            int e = t + i * 256;
            int r = e >> 4, c4 = e & 15;
            float4 v = *(const float4*)&B[(size_t)(k0 + r) * Nc + col0 + c4 * 4];
            *(float4*)&sB[r][c4 * 4] = v;
        }
        __syncthreads();
        #pragma unroll
        for (int kk = 0; kk < 32; ++kk) {
            float4 a = *(const float4*)&sAT[kk][ty * 4];
            float4 b = *(const float4*)&sB[kk][tx * 4];
            acc[0][0] += a.x * b.x; acc[0][1] += a.x * b.y; acc[0][2] += a.x * b.z; acc[0][3] += a.x * b.w;
            acc[1][0] += a.y * b.x; acc[1][1] += a.y * b.y; acc[1][2] += a.y * b.z; acc[1][3] += a.y * b.w;
            acc[2][0] += a.z * b.x; acc[2][1] += a.z * b.y; acc[2][2] += a.z * b.z; acc[2][3] += a.z * b.w;
            acc[3][0] += a.w * b.x; acc[3][1] += a.w * b.y; acc[3][2] += a.w * b.z; acc[3][3] += a.w * b.w;
        }
        __syncthreads();
    }
    #pragma unroll
    for (int j = 0; j < 4; ++j) {
        int gr = row0 + ty * 4 + j;
        if (gr < M) {
            float4 v = make_float4(acc[j][0], acc[j][1], acc[j][2], acc[j][3]);
            *(float4*)&Cmat[(size_t)gr * Nc + col0 + tx * 4] = v;
        }
    }
}

// ---------------- GEMM bf16 out (for h4b) ----------------------------------------
__global__ __launch_bounds__(256) void gemm_bf_kernel(const float* __restrict__ A,
        const float* __restrict__ B, unsigned short* __restrict__ Cb,
        int M, int K, int Nc) {
    __shared__ float sAT[32][68];
    __shared__ float sB[32][68];
    int t = threadIdx.x;
    int col0 = blockIdx.x * 64;
    int row0 = blockIdx.y * 64;
    int tx = t & 15, ty = t >> 4;
    float acc[4][4] = {};
    for (int k0 = 0; k0 < K; k0 += 32) {
        #pragma unroll
        for (int i = 0; i < 2; ++i) {
            int e = t + i * 256;
            int r = e >> 3, c4 = e & 7;
            int gr = row0 + r;
            float4 v = make_float4(0.f, 0.f, 0.f, 0.f);
            if (gr < M) v = *(const float4*)&A[(size_t)gr * K + k0 + c4 * 4];
            sAT[c4 * 4 + 0][r] = v.x;
            sAT[c4 * 4 + 1][r] = v.y;
            sAT[c4 * 4 + 2][r] = v.z;
            sAT[c4 * 4 + 3][r] = v.w;
        }
        #pragma unroll
        for (int i = 0; i < 2; ++i) {
            int e = t + i * 256;
            int r = e >> 4, c4 = e & 15;
            float4 v = *(const float4*)&B[(size_t)(k0 + r) * Nc + col0 + c4 * 4];
            *(float4*)&sB[r][c4 * 4] = v;
        }
        __syncthreads();
        #pragma unroll
        for (int kk = 0; kk < 32; ++kk) {
            float4 a = *(const float4*)&sAT[kk][ty * 4];
            float4 b = *(const float4*)&sB[kk][tx * 4];
            acc[0][0] += a.x * b.x; acc[0][1] += a.x * b.y; acc[0][2] += a.x * b.z; acc[0][3] += a.x * b.w;
            acc[1][0] += a.y * b.x; acc[1][1] += a.y * b.y; acc[1][2] += a.y * b.z; acc[1][3] += a.y * b.w;
            acc[2][0] += a.z * b.x; acc[2][1] += a.z * b.y; acc[2][2] += a.z * b.z; acc[2][3] += a.z * b.w;
            acc[3][0] += a.w * b.x; acc[3][1] += a.w * b.y; acc[3][2] += a.w * b.z; acc[3][3] += a.w * b.w;
        }
        __syncthreads();
    }
    #pragma unroll
    for (int j = 0; j < 4; ++j) {
        int gr = row0 + ty * 4 + j;
        if (gr < M) {
            ushort4 v;
            v.x = f2bf(acc[j][0]); v.y = f2bf(acc[j][1]);
            v.z = f2bf(acc[j][2]); v.w = f2bf(acc[j][3]);
            *(ushort4*)&Cb[(size_t)gr * Nc + col0 + tx * 4] = v;
        }
    }
}

// ---------------- misc fused: gbound + permW1 + permW2 ----------------------------
__global__ void misc_kernel(const int* __restrict__ bidx, int* __restrict__ gstart,
        const float* __restrict__ W1, float* __restrict__ W1p,
        const float* __restrict__ W2, float* __restrict__ W2p) {
    int b = blockIdx.x, t = threadIdx.x;
    if (b < 79) {
        int i = b * 256 + t;
        if (i >= NN) return;
        int cur = bidx[i];
        if (i == 0) {
            for (int g = 0; g <= cur; ++g) gstart[g] = 0;
        } else {
            int prev = bidx[i - 1];
            for (int g = prev + 1; g <= cur; ++g) gstart[g] = i;
        }
        if (i == NN - 1) {
            for (int g = cur + 1; g <= GG; ++g) gstart[g] = NN;
        }
    } else if (b < 207) {
        int i = (b - 79) * 256 + t;       // i < FIN*256
        int col = i & 255;
        int h = col & 3, c = col >> 2;
        int f = i >> 8;
        W1p[i] = W1[f * 256 + h * 64 + c];
    } else {
        int i = (b - 207) * 256 + t;      // i < CC*256
        int col = i & 255;
        int h = col & 3, c = col >> 2;
        int f = i >> 8;
        W2p[i] = W2[f * 256 + h * 64 + c];
    }
}

// ---------------- attention logits from bf16 h4b [N][C][H] ------------------------
__global__ __launch_bounds__(256) void att_kernel(const unsigned short* __restrict__ h4b,
        const float* __restrict__ a_src, const float* __restrict__ a_dst,
        float4* __restrict__ es4, float4* __restrict__ ed4) {
    int n = blockIdx.x * 4 + (threadIdx.x >> 6);
    if (n >= NN) return;
    int lane = threadIdx.x & 63;
    ushort4 hv = *(const ushort4*)&h4b[(size_t)n * HC + lane * 4];
    float vx = bf2f(hv.x), vy = bf2f(hv.y), vz = bf2f(hv.z), vw = bf2f(hv.w);
    float s0 = vx * a_src[0 * CC + lane];
    float s1 = vy * a_src[1 * CC + lane];
    float s2 = vz * a_src[2 * CC + lane];
    float s3 = vw * a_src[3 * CC + lane];
    float d0 = vx * a_dst[0 * CC + lane];
    float d1 = vy * a_dst[1 * CC + lane];
    float d2 = vz * a_dst[2 * CC + lane];
    float d3 = vw * a_dst[3 * CC + lane];
    #pragma unroll
    for (int off = 32; off; off >>= 1) {
        s0 += __shfl_down(s0, off); s1 += __shfl_down(s1, off);
        s2 += __shfl_down(s2, off); s3 += __shfl_down(s3, off);
        d0 += __shfl_down(d0, off); d1 += __shfl_down(d1, off);
        d2 += __shfl_down(d2, off); d3 += __shfl_down(d3, off);
    }
    if (lane == 0) {
        es4[n] = make_float4(s0, s1, s2, s3);
        ed4[n] = make_float4(d0, d1, d2, d3);
    }
}

// ---------------- CSR build ----------------
__global__ void count_kernel(const int* __restrict__ ei, int* __restrict__ deg) {
    int i = blockIdx.x * 256 + threadIdx.x;
    if (i >= ETOT) return;
    int d = (i < EE) ? ei[EE + i] : (i - EE);
    atomicAdd(&deg[d], 1);
}

__global__ __launch_bounds__(256) void scan1(const int* __restrict__ deg,
        int* __restrict__ off, int* __restrict__ part) {
    __shared__ int buf[256];
    int b = blockIdx.x, t = threadIdx.x;
    int i = b * 256 + t;
    int v = (i < NN) ? deg[i] : 0;
    buf[t] = v; __syncthreads();
    for (int s = 1; s < 256; s <<= 1) {
        int x = (t >= s) ? buf[t - s] : 0;
        __syncthreads();
        buf[t] += x;
        __syncthreads();
    }
    int incl = buf[t];
    if (i < NN) off[i] = incl - v;
    if (t == 255) part[b] = incl;
}

__global__ __launch_bounds__(256) void scan23(int* __restrict__ off,
        const int* __restrict__ part) {
    __shared__ int buf[128];
    int t = threadIdx.x, b = blockIdx.x;
    if (t < 128) buf[t] = (t < (int)gridDim.x) ? part[t] : 0;
    __syncthreads();
    for (int s = 1; s < 128; s <<= 1) {
        int x = (t >= s && t < 128) ? buf[t - s] : 0;
        __syncthreads();
        if (t < 128) buf[t] += x;
        __syncthreads();
    }
    int prefix = (b == 0) ? 0 : buf[b - 1];
    int i = b * 256 + t;
    if (i < NN) off[i] += prefix;
    if (i == 0) off[NN] = ETOT;
}

__global__ void fill_kernel(const int* __restrict__ ei, const int* __restrict__ off,
        int* __restrict__ cursor, int* __restrict__ csr_src) {
    int i = blockIdx.x * 256 + threadIdx.x;
    if (i >= ETOT) return;
    int s, d;
    if (i < EE) { s = ei[i]; d = ei[EE + i]; } else { s = i - EE; d = i - EE; }
    int pos = atomicAdd(&cursor[d], 1);
    csr_src[off[d] + pos] = s;
}

// ---------------- per-destination GAT aggregation (bf16 gather) --------------------
__device__ __forceinline__ void edge_acc(const float4 esv, const ushort4 hv,
        const float4 edn, float4& acc, float4& ssum) {
    float e0 = esv.x + edn.x; e0 = fmaxf(e0, 0.2f * e0); float w0 = __expf(e0);
    float e1 = esv.y + edn.y; e1 = fmaxf(e1, 0.2f * e1); float w1 = __expf(e1);
    float e2 = esv.z + edn.z; e2 = fmaxf(e2, 0.2f * e2); float w2 = __expf(e2);
    float e3 = esv.w + edn.w; e3 = fmaxf(e3, 0.2f * e3); float w3 = __expf(e3);
    acc.x += w0 * bf2f(hv.x); ssum.x += w0;
    acc.y += w1 * bf2f(hv.y); ssum.y += w1;
    acc.z += w2 * bf2f(hv.z); ssum.z += w2;
    acc.w += w3 * bf2f(hv.w); ssum.w += w3;
}

// 4 waves/block; wave = node; lane = channel; edge loop unrolled x4.
__global__ __launch_bounds__(256) void aggr_kernel(const unsigned short* __restrict__ h4b,
        const float4* __restrict__ es4, const float4* __restrict__ ed4,
        const int* __restrict__ off, const int* __restrict__ csr_src,
        const float* __restrict__ bias, float* __restrict__ out) {
    int n = blockIdx.x * 4 + (threadIdx.x >> 6);
    if (n >= NN) return;
    int lane = threadIdx.x & 63;
    float4 edn = ed4[n];
    float4 acc = make_float4(0.f, 0.f, 0.f, 0.f);
    float4 ssum = make_float4(0.f, 0.f, 0.f, 0.f);
    int beg = off[n], end = off[n + 1];
    int j = beg;
    for (; j + 4 <= end; j += 4) {
        int s0 = csr_src[j + 0];
        int s1 = csr_src[j + 1];
        int s2 = csr_src[j + 2];
        int s3 = csr_src[j + 3];
        float4 E0 = es4[s0];
        float4 E1 = es4[s1];
        float4 E2 = es4[s2];
        float4 E3 = es4[s3];
        ushort4 v0 = *(const ushort4*)&h4b[(size_t)s0 * HC + lane * 4];
        ushort4 v1 = *(const ushort4*)&h4b[(size_t)s1 * HC + lane * 4];
        ushort4 v2 = *(const ushort4*)&h4b[(size_t)s2 * HC + lane * 4];
        ushort4 v3 = *(const ushort4*)&h4b[(size_t)s3 * HC + lane * 4];
        edge_acc(E0, v0, edn, acc, ssum);
        edge_acc(E1, v1, edn, acc, ssum);
        edge_acc(E2, v2, edn, acc, ssum);
        edge_acc(E3, v3, edn, acc, ssum);
    }
    for (; j < end; ++j) {
        int s = csr_src[j];
        float4 E = es4[s];
        ushort4 v = *(const ushort4*)&h4b[(size_t)s * HC + lane * 4];
        edge_acc(E, v, edn, acc, ssum);
    }
    float val = 0.25f * (acc.x / (ssum.x + 1e-16f) + acc.y / (ssum.y + 1e-16f) +
                         acc.z / (ssum.z + 1e-16f) + acc.w / (ssum.w + 1e-16f)) + bias[lane];
    out[n * CC + lane] = val;
}

// ---------------- BN statistics ----------------
__global__ __launch_bounds__(256) void bnstat_kernel(const float* __restrict__ x,
        float* __restrict__ stats) {
    int t = threadIdx.x;
    int ch = t & 63, slice = t >> 6;
    float s = 0.f, q = 0.f;
    for (int n = blockIdx.x * 4 + slice; n < NN; n += gridDim.x * 4) {
        float v = x[n * CC + ch];
        s += v; q += v * v;
    }
    __shared__ float ls[4][64], lq[4][64];
    ls[slice][ch] = s; lq[slice][ch] = q;
    __syncthreads();
    if (slice == 0) {
        s = ls[0][ch] + ls[1][ch] + ls[2][ch] + ls[3][ch];
        q = lq[0][ch] + lq[1][ch] + lq[2][ch] + lq[3][ch];
        atomicAdd(&stats[ch], s);
        atomicAdd(&stats[CC + ch], q);
    }
}

__device__ __forceinline__ float gelu_exact(float v) {
    return 0.5f * v * (1.f + erff(v * 0.70710678118654752f));
}

__global__ __launch_bounds__(256) void bnapply1_kernel(const float* __restrict__ gout,
        const float* __restrict__ stats, const float* __restrict__ g,
        const float* __restrict__ be, const float* __restrict__ skip,
        const float* __restrict__ bskip, float* __restrict__ outm) {
    int i = blockIdx.x * 256 + threadIdx.x;
    if (i >= NN * CC) return;
    int ch = i & 63;
    float mu  = stats[ch] * (1.f / NN);
    float var = stats[CC + ch] * (1.f / NN) - mu * mu;
    float inv = rsqrtf(var + BN_EPS);
    float v = (gout[i] - mu) * inv * g[ch] + be[ch] + skip[i] + bskip[ch];
    outm[i] = gelu_exact(v);
}

__global__ __launch_bounds__(256) void bnapply2_kernel(const float* __restrict__ gout,
        const float* __restrict__ stats, const float* __restrict__ g,
        const float* __restrict__ be, const float* __restrict__ resid,
        float* __restrict__ outm) {
    int i = blockIdx.x * 256 + threadIdx.x;
    if (i >= NN * CC) return;
    int ch = i & 63;
    float mu  = stats[ch] * (1.f / NN);
    float var = stats[CC + ch] * (1.f / NN) - mu * mu;
    float inv = rsqrtf(var + BN_EPS);
    float v = (gout[i] - mu) * inv * g[ch] + be[ch] + resid[i];
    outm[i] = gelu_exact(v);
}

// ---------------- pooling ----------------
__global__ __launch_bounds__(1024) void pool_kernel(const float* __restrict__ h2,
        const int* __restrict__ gstart, float* __restrict__ out) {
    __shared__ float4 sdata[64][17];
    int g = blockIdx.x;
    int t = threadIdx.x;
    int c4 = t & 15;
    int slice = t >> 4;
    int start = gstart[g], end = gstart[g + 1];
    float4 acc = make_float4(0.f, 0.f, 0.f, 0.f);
    for (int n = start + slice; n < end; n += 64) {
        float4 v = *(const float4*)&h2[(size_t)n * CC + c4 * 4];
        acc.x += v.x; acc.y += v.y; acc.z += v.z; acc.w += v.w;
    }
    sdata[slice][c4] = acc;
    __syncthreads();
    #pragma unroll
    for (int s = 32; s >= 1; s >>= 1) {
        if (slice < s) {
            float4 o = sdata[slice + s][c4];
            acc.x += o.x; acc.y += o.y; acc.z += o.z; acc.w += o.w;
            sdata[slice][c4] = acc;
        }
        __syncthreads();
    }
    if (slice == 0) {
        int cnt = end - start;
        float inv = 1.f / (float)((cnt > 0) ? cnt : 1);
        float4 r = make_float4(acc.x * inv, acc.y * inv, acc.z * inv, acc.w * inv);
        *(float4*)&out[g * CC + c4 * 4] = r;
    }
}

extern "C" void kernel_launch(void* const* d_in, const int* in_sizes, int n_in,
                              void* d_out, int out_size, void* d_ws, size_t ws_size,
                              hipStream_t stream) {
    const float* x      = (const float*)d_in[0];
    const float* W1     = (const float*)d_in[1];
    const float* a_src1 = (const float*)d_in[2];
    const float* a_dst1 = (const float*)d_in[3];
    const float* b1     = (const float*)d_in[4];
    const float* Wskip  = (const float*)d_in[5];
    const float* bskip  = (const float*)d_in[6];
    const float* g1     = (const float*)d_in[7];
    const float* be1    = (const float*)d_in[8];
    const float* W2     = (const float*)d_in[9];
    const float* a_src2 = (const float*)d_in[10];
    const float* a_dst2 = (const float*)d_in[11];
    const float* b2     = (const float*)d_in[12];
    const float* g2     = (const float*)d_in[13];
    const float* be2    = (const float*)d_in[14];
    const int*   ei     = (const int*)d_in[15];
    const int*   bidx   = (const int*)d_in[16];
    float* out = (float*)d_out;

    char* w = (char*)d_ws;
    size_t o = 0;
    auto alloc = [&](size_t bytes) -> void* {
        void* p = w + o;
        o = (o + bytes + 255) & ~(size_t)255;
        return p;
    };

    unsigned short* h4b = (unsigned short*)alloc((size_t)NN * HC * 2);  // bf16 [N][C][H]
    float4* es4 = (float4*)alloc((size_t)NN * 16);
    float4* ed4 = (float4*)alloc((size_t)NN * 16);
    float* skip = (float*)alloc((size_t)NN * CC * 4);  // layer1 skip; reused as h2 output
    float* gout = (float*)alloc((size_t)NN * CC * 4);
    float* hmid = (float*)alloc((size_t)NN * CC * 4);
    float* W1p  = (float*)alloc((size_t)FIN * HC * 4);
    float* W2p  = (float*)alloc((size_t)CC * HC * 4);
    int* off    = (int*)alloc((size_t)(NN + 1) * 4);
    int* csr    = (int*)alloc((size_t)ETOT * 4);
    int* gstart = (int*)alloc((size_t)(GG + 1) * 4);
    // ---- zero region (contiguous) ----
    char* zbase = w + o;
    int* deg    = (int*)alloc((size_t)NN * 4);
    int* cursor = (int*)alloc((size_t)NN * 4);
    int* part   = (int*)alloc(128 * 4);
    float* stats1 = (float*)alloc(128 * 4);
    float* stats2 = (float*)alloc(128 * 4);
    size_t zbytes = (size_t)((w + o) - zbase);
    float* h2 = skip;  // reuse

    hipMemsetAsync(zbase, 0, zbytes, stream);

    int ebk = (ETOT + 255) / 256;
    int nbk = (NN + 255) / 256;     // 79

    misc_kernel<<<79 + 128 + 64, 256, 0, stream>>>(bidx, gstart, W1, W1p, W2, W2p);
    count_kernel<<<ebk, 256, 0, stream>>>(ei, deg);
    scan1<<<nbk, 256, 0, stream>>>(deg, off, part);
    scan23<<<nbk, 256, 0, stream>>>(off, part);
    fill_kernel<<<ebk, 256, 0, stream>>>(ei, off, cursor, csr);

    dim3 gemm_blk(256);
    dim3 g_h(HC / 64, (NN + 63) / 64);
    dim3 g_s(CC / 64, (NN + 63) / 64);
    int nodeblk = (NN + 3) / 4;

    // ---- layer 1 ----
    gemm_bf_kernel<<<g_h, gemm_blk, 0, stream>>>(x, W1p, h4b, NN, FIN, HC);
    gemm_kernel<<<g_s, gemm_blk, 0, stream>>>(x, Wskip, skip, NN, FIN, CC);
    att_kernel<<<nodeblk, 256, 0, stream>>>(h4b, a_src1, a_dst1, es4, ed4);
    aggr_kernel<<<nodeblk, 256, 0, stream>>>(h4b, es4, ed4, off, csr, b1, gout);
    bnstat_kernel<<<128, 256, 0, stream>>>(gout, stats1);
    bnapply1_kernel<<<(NN * CC + 255) / 256, 256, 0, stream>>>(
        gout, stats1, g1, be1, skip, bskip, hmid);

    // ---- layer 2 ----
    gemm_bf_kernel<<<g_h, gemm_blk, 0, stream>>>(hmid, W2p, h4b, NN, CC, HC);
    att_kernel<<<nodeblk, 256, 0, stream>>>(h4b, a_src2, a_dst2, es4, ed4);
    aggr_kernel<<<nodeblk, 256, 0, stream>>>(h4b, es4, ed4, off, csr, b2, gout);
    bnstat_kernel<<<128, 256, 0, stream>>>(gout, stats2);
    bnapply2_kernel<<<(NN * CC + 255) / 256, 256, 0, stream>>>(
        gout, stats2, g2, be2, hmid, h2);

    // ---- pool ----
    pool_kernel<<<GG, 1024, 0, stream>>>(h2, gstart, out);
}